// Round 1
// baseline (394.450 us; speedup 1.0000x reference)
//
#include <hip/hip_runtime.h>
#include <hip/hip_bf16.h>
#include <cstdint>
#include <cstddef>

#define S_LEN 2048
#define D_MODEL 1024
#define N_HEADS 16
#define DEPTH 64
#define BATCH 4

typedef __attribute__((ext_vector_type(4))) float f32x4;
typedef __attribute__((ext_vector_type(8))) short bf16x8;
typedef __attribute__((ext_vector_type(4))) unsigned short us4;
typedef __attribute__((ext_vector_type(8))) unsigned short us8;

__device__ __forceinline__ unsigned short f2bf(float f) {
  unsigned int u = __builtin_bit_cast(unsigned int, f);
  u += 0x7FFFu + ((u >> 16) & 1u);   // round-to-nearest-even
  return (unsigned short)(u >> 16);
}

// ---------------------------------------------------------------------------
// Weight transpose + fp32 -> bf16 cast:  Wt[n][k] = W[k][n]
// ---------------------------------------------------------------------------
__global__ __launch_bounds__(256) void transpose_cast(const float* __restrict__ W,
                                                      unsigned short* __restrict__ Wt,
                                                      int N) {
  __shared__ float tile[32][33];
  int bx = blockIdx.x * 32;  // n-range
  int by = blockIdx.y * 32;  // k-range
  int tx = threadIdx.x, ty = threadIdx.y;  // 32 x 8
#pragma unroll
  for (int i = 0; i < 4; ++i)
    tile[ty + i * 8][tx] = W[(size_t)(by + ty + i * 8) * N + bx + tx];
  __syncthreads();
#pragma unroll
  for (int i = 0; i < 4; ++i)
    Wt[(size_t)(bx + ty + i * 8) * N + by + tx] = f2bf(tile[tx][ty + i * 8]);
}

// ---------------------------------------------------------------------------
// GEMM:  C[M][N] = A[M][K] @ Bt[N][K]^T + bias
// A is fp32 (converted to bf16 during staging) or bf16. Output fp32 or bf16.
// 128x128 tile, BK=64, 4 waves (2x2), acc 4x4 of 16x16 frags per wave.
// ---------------------------------------------------------------------------
template <bool A_IS_F32, bool OUT_F32>
__global__ __launch_bounds__(256) void gemm_bt(const void* __restrict__ Aptr,
                                               const unsigned short* __restrict__ Bt,
                                               const float* __restrict__ bias,
                                               void* __restrict__ Cptr,
                                               int M, int N, int K) {
  __shared__ unsigned short a_lds[128][72];
  __shared__ unsigned short b_lds[128][72];

  int tid = threadIdx.x;
  int wave = tid >> 6, lane = tid & 63;
  int l15 = lane & 15, lg = lane >> 4;
  int row0 = blockIdx.x * 128;
  int col0 = blockIdx.y * 128;
  int wm = wave >> 1, wn = wave & 1;

  const float* Af = (const float*)Aptr;
  const unsigned short* Ah = (const unsigned short*)Aptr;

  f32x4 acc[4][4] = {};

  for (int k0 = 0; k0 < K; k0 += 64) {
    __syncthreads();
    // ---- stage A tile (128 x 64) ----
    if constexpr (A_IS_F32) {
      int r = tid >> 4, c4 = tid & 15;
#pragma unroll
      for (int rep = 0; rep < 8; ++rep) {
        f32x4 v = *(const f32x4*)(Af + (size_t)(row0 + rep * 16 + r) * K + k0 + c4 * 4);
        us4 h = {f2bf(v[0]), f2bf(v[1]), f2bf(v[2]), f2bf(v[3])};
        *(us4*)&a_lds[rep * 16 + r][c4 * 4] = h;
      }
    } else {
      int r = tid >> 3, c8 = tid & 7;
#pragma unroll
      for (int rep = 0; rep < 4; ++rep) {
        us8 v = *(const us8*)(Ah + (size_t)(row0 + rep * 32 + r) * K + k0 + c8 * 8);
        *(us8*)&a_lds[rep * 32 + r][c8 * 8] = v;
      }
    }
    // ---- stage B tile (128 x 64) from Bt [N][K] ----
    {
      int r = tid >> 3, c8 = tid & 7;
#pragma unroll
      for (int rep = 0; rep < 4; ++rep) {
        us8 v = *(const us8*)(Bt + (size_t)(col0 + rep * 32 + r) * K + k0 + c8 * 8);
        *(us8*)&b_lds[rep * 32 + r][c8 * 8] = v;
      }
    }
    __syncthreads();
    // ---- compute ----
#pragma unroll
    for (int kk = 0; kk < 2; ++kk) {
      bf16x8 af[4], bfr[4];
#pragma unroll
      for (int i = 0; i < 4; ++i)
        af[i] = *(const bf16x8*)&a_lds[wm * 64 + i * 16 + l15][kk * 32 + lg * 8];
#pragma unroll
      for (int j = 0; j < 4; ++j)
        bfr[j] = *(const bf16x8*)&b_lds[wn * 64 + j * 16 + l15][kk * 32 + lg * 8];
#pragma unroll
      for (int i = 0; i < 4; ++i)
#pragma unroll
        for (int j = 0; j < 4; ++j)
          acc[i][j] = __builtin_amdgcn_mfma_f32_16x16x32_bf16(af[i], bfr[j], acc[i][j], 0, 0, 0);
    }
  }

  // ---- epilogue ----
#pragma unroll
  for (int i = 0; i < 4; ++i) {
#pragma unroll
    for (int j = 0; j < 4; ++j) {
      int col = col0 + wn * 64 + j * 16 + l15;
      float bv = bias[col];
#pragma unroll
      for (int r = 0; r < 4; ++r) {
        int row = row0 + wm * 64 + i * 16 + lg * 4 + r;
        float v = acc[i][j][r] + bv;
        if constexpr (OUT_F32)
          ((float*)Cptr)[(size_t)row * N + col] = v;
        else
          ((unsigned short*)Cptr)[(size_t)row * N + col] = f2bf(v);
      }
    }
  }
}

// ---------------------------------------------------------------------------
// Causal flash attention over bf16 Q/K/V stored [B, S, D] (head h at cols
// h*64..h*64+63). One block per (q-tile of 64, b*h). 4 waves x 16 q-rows.
// ---------------------------------------------------------------------------
__global__ __launch_bounds__(256) void attn_kernel(const unsigned short* __restrict__ Qp,
                                                   const unsigned short* __restrict__ Kp,
                                                   const unsigned short* __restrict__ Vp,
                                                   unsigned short* __restrict__ Op) {
  __shared__ unsigned short k_lds[64][72];
  __shared__ unsigned short vt_lds[64][72];   // vt_lds[d][k]
  __shared__ unsigned short p_lds[4][16][72]; // per-wave P tile

  int tid = threadIdx.x;
  int w = tid >> 6, lane = tid & 63;
  int l15 = lane & 15, lg = lane >> 4;
  int qb = blockIdx.x;
  int bh = blockIdx.y;
  int b = bh >> 4, h = bh & 15;
  int q0 = qb * 64;

  // Q fragments for this wave's 16 q-rows (A-frag: row = lane&15, k = lg*8..)
  bf16x8 qf[2];
  {
    const unsigned short* qp =
        Qp + ((size_t)(b * S_LEN + q0 + w * 16 + l15)) * D_MODEL + h * DEPTH;
    qf[0] = *(const bf16x8*)(qp + lg * 8);
    qf[1] = *(const bf16x8*)(qp + 32 + lg * 8);
  }

  float m_run[4], l_run[4];
  f32x4 acc_o[4];
#pragma unroll
  for (int r = 0; r < 4; ++r) { m_run[r] = -1e30f; l_run[r] = 0.f; }
#pragma unroll
  for (int d = 0; d < 4; ++d) acc_o[d] = (f32x4){0.f, 0.f, 0.f, 0.f};

  const float scale = 0.125f;  // 1/sqrt(64)

  for (int kb = 0; kb <= qb; ++kb) {
    int k0 = kb * 64;
    __syncthreads();
    // ---- stage K tile and V^T tile ----
    {
      int r = tid >> 2, cb = (tid & 3) * 16;
      const unsigned short* kp =
          Kp + ((size_t)(b * S_LEN + k0 + r)) * D_MODEL + h * DEPTH + cb;
      us8 v0 = *(const us8*)kp;
      us8 v1 = *(const us8*)(kp + 8);
      *(us8*)&k_lds[r][cb] = v0;
      *(us8*)&k_lds[r][cb + 8] = v1;
      const unsigned short* vp =
          Vp + ((size_t)(b * S_LEN + k0 + r)) * D_MODEL + h * DEPTH + cb;
      us8 w0 = *(const us8*)vp;
      us8 w1 = *(const us8*)(vp + 8);
#pragma unroll
      for (int e = 0; e < 8; ++e) vt_lds[cb + e][r] = w0[e];
#pragma unroll
      for (int e = 0; e < 8; ++e) vt_lds[cb + 8 + e][r] = w1[e];
    }
    __syncthreads();

    // ---- S = Q @ K^T ----
    f32x4 s[4];
#pragma unroll
    for (int nf = 0; nf < 4; ++nf) s[nf] = (f32x4){0.f, 0.f, 0.f, 0.f};
#pragma unroll
    for (int kk = 0; kk < 2; ++kk) {
      bf16x8 kf[4];
#pragma unroll
      for (int nf = 0; nf < 4; ++nf)
        kf[nf] = *(const bf16x8*)&k_lds[nf * 16 + l15][kk * 32 + lg * 8];
#pragma unroll
      for (int nf = 0; nf < 4; ++nf)
        s[nf] = __builtin_amdgcn_mfma_f32_16x16x32_bf16(qf[kk], kf[nf], s[nf], 0, 0, 0);
    }

    // ---- scale + causal mask ----
    bool diag = (kb == qb);
    float sv[4][4];
#pragma unroll
    for (int nf = 0; nf < 4; ++nf)
#pragma unroll
      for (int r = 0; r < 4; ++r) {
        float x = s[nf][r] * scale;
        if (diag) {
          int qrow = w * 16 + lg * 4 + r;
          int krow = nf * 16 + l15;
          if (krow > qrow) x = -1e10f;
        }
        sv[nf][r] = x;
      }

    // ---- online softmax ----
    float mnew[4], corr[4], psum[4];
#pragma unroll
    for (int r = 0; r < 4; ++r) {
      float mx = fmaxf(fmaxf(sv[0][r], sv[1][r]), fmaxf(sv[2][r], sv[3][r]));
#pragma unroll
      for (int off = 1; off < 16; off <<= 1)
        mx = fmaxf(mx, __shfl_xor(mx, off, 16));
      mnew[r] = fmaxf(m_run[r], mx);
      corr[r] = __expf(m_run[r] - mnew[r]);
      m_run[r] = mnew[r];
    }
#pragma unroll
    for (int r = 0; r < 4; ++r) psum[r] = 0.f;
#pragma unroll
    for (int nf = 0; nf < 4; ++nf)
#pragma unroll
      for (int r = 0; r < 4; ++r) {
        float p = __expf(sv[nf][r] - mnew[r]);
        psum[r] += p;
        p_lds[w][lg * 4 + r][nf * 16 + l15] = f2bf(p);
      }
#pragma unroll
    for (int r = 0; r < 4; ++r) {
      float ps = psum[r];
#pragma unroll
      for (int off = 1; off < 16; off <<= 1)
        ps += __shfl_xor(ps, off, 16);
      l_run[r] = l_run[r] * corr[r] + ps;
    }
#pragma unroll
    for (int d = 0; d < 4; ++d)
#pragma unroll
      for (int r = 0; r < 4; ++r) acc_o[d][r] *= corr[r];

    // ---- O += P @ V ----  (p_lds write->read is within-wave; compiler
    // inserts the lgkmcnt wait since it cannot prove independence)
#pragma unroll
    for (int kk = 0; kk < 2; ++kk) {
      bf16x8 pf = *(const bf16x8*)&p_lds[w][l15][kk * 32 + lg * 8];
#pragma unroll
      for (int d = 0; d < 4; ++d) {
        bf16x8 vf = *(const bf16x8*)&vt_lds[d * 16 + l15][kk * 32 + lg * 8];
        acc_o[d] = __builtin_amdgcn_mfma_f32_16x16x32_bf16(pf, vf, acc_o[d], 0, 0, 0);
      }
    }
  }

  // ---- finalize: divide by row sum, store bf16 ----
#pragma unroll
  for (int r = 0; r < 4; ++r) {
    float inv = 1.0f / l_run[r];
    int qrow = q0 + w * 16 + lg * 4 + r;
    unsigned short* op = Op + ((size_t)(b * S_LEN + qrow)) * D_MODEL + h * DEPTH;
#pragma unroll
    for (int d = 0; d < 4; ++d)
      op[d * 16 + l15] = f2bf(acc_o[d][r] * inv);
  }
}

// ---------------------------------------------------------------------------
extern "C" void kernel_launch(void* const* d_in, const int* in_sizes, int n_in,
                              void* d_out, int out_size, void* d_ws, size_t ws_size,
                              hipStream_t stream) {
  const float* q  = (const float*)d_in[0];
  const float* v  = (const float*)d_in[1];
  const float* k  = (const float*)d_in[2];
  const float* Wq = (const float*)d_in[3];
  const float* bq = (const float*)d_in[4];
  const float* Wk = (const float*)d_in[5];
  const float* bk = (const float*)d_in[6];
  const float* Wv = (const float*)d_in[7];
  const float* bv = (const float*)d_in[8];
  const float* Wo = (const float*)d_in[9];
  const float* bo = (const float*)d_in[10];
  // d_in[11] = mask scalar; always 1 (causal) for this problem.

  char* ws = (char*)d_ws;
  const size_t WSZ = (size_t)D_MODEL * D_MODEL * 2;        // 2 MB per weight
  const size_t XSZ = (size_t)BATCH * S_LEN * D_MODEL * 2;  // 16 MB per activation
  unsigned short* Wqt = (unsigned short*)(ws);
  unsigned short* Wkt = (unsigned short*)(ws + WSZ);
  unsigned short* Wvt = (unsigned short*)(ws + 2 * WSZ);
  unsigned short* Wot = (unsigned short*)(ws + 3 * WSZ);
  unsigned short* Qp  = (unsigned short*)(ws + 4 * WSZ);
  unsigned short* Kp  = (unsigned short*)(ws + 4 * WSZ + XSZ);
  unsigned short* Vp  = (unsigned short*)(ws + 4 * WSZ + 2 * XSZ);
  unsigned short* AO  = (unsigned short*)(ws + 4 * WSZ + 3 * XSZ);

  dim3 tb(32, 8);
  dim3 tg(D_MODEL / 32, D_MODEL / 32);
  hipLaunchKernelGGL(transpose_cast, tg, tb, 0, stream, Wq, Wqt, D_MODEL);
  hipLaunchKernelGGL(transpose_cast, tg, tb, 0, stream, Wk, Wkt, D_MODEL);
  hipLaunchKernelGGL(transpose_cast, tg, tb, 0, stream, Wv, Wvt, D_MODEL);
  hipLaunchKernelGGL(transpose_cast, tg, tb, 0, stream, Wo, Wot, D_MODEL);

  const int M = BATCH * S_LEN;
  dim3 gg(M / 128, D_MODEL / 128);
  hipLaunchKernelGGL((gemm_bt<true, false>), gg, dim3(256), 0, stream,
                     (const void*)q, Wqt, bq, (void*)Qp, M, D_MODEL, D_MODEL);
  hipLaunchKernelGGL((gemm_bt<true, false>), gg, dim3(256), 0, stream,
                     (const void*)k, Wkt, bk, (void*)Kp, M, D_MODEL, D_MODEL);
  hipLaunchKernelGGL((gemm_bt<true, false>), gg, dim3(256), 0, stream,
                     (const void*)v, Wvt, bv, (void*)Vp, M, D_MODEL, D_MODEL);

  dim3 ag(S_LEN / 64, BATCH * N_HEADS);
  hipLaunchKernelGGL(attn_kernel, ag, dim3(256), 0, stream, Qp, Kp, Vp, AO);

  hipLaunchKernelGGL((gemm_bt<false, true>), gg, dim3(256), 0, stream,
                     (const void*)AO, Wot, bo, d_out, M, D_MODEL, D_MODEL);
}

// Round 2
// 263.931 us; speedup vs baseline: 1.4945x; 1.4945x over previous
//
#include <hip/hip_runtime.h>
#include <hip/hip_bf16.h>
#include <cstdint>
#include <cstddef>

#define S_LEN 2048
#define D_MODEL 1024
#define N_HEADS 16
#define DEPTH 64
#define BATCH 4

typedef __attribute__((ext_vector_type(4))) float f32x4;
typedef __attribute__((ext_vector_type(8))) short bf16x8;
typedef __attribute__((ext_vector_type(4))) unsigned short us4;
typedef __attribute__((ext_vector_type(8))) unsigned short us8;

__device__ __forceinline__ unsigned short f2bf(float f) {
  unsigned int u = __builtin_bit_cast(unsigned int, f);
  u += 0x7FFFu + ((u >> 16) & 1u);   // round-to-nearest-even
  return (unsigned short)(u >> 16);
}

// ---------------------------------------------------------------------------
// Weight transpose + fp32 -> bf16 cast:  Wt[n][k] = W[k][n]
// ---------------------------------------------------------------------------
__global__ __launch_bounds__(256) void transpose_cast(const float* __restrict__ W,
                                                      unsigned short* __restrict__ Wt,
                                                      int N) {
  __shared__ float tile[32][33];
  int bx = blockIdx.x * 32;  // n-range
  int by = blockIdx.y * 32;  // k-range
  int tx = threadIdx.x, ty = threadIdx.y;  // 32 x 8
#pragma unroll
  for (int i = 0; i < 4; ++i)
    tile[ty + i * 8][tx] = W[(size_t)(by + ty + i * 8) * N + bx + tx];
  __syncthreads();
#pragma unroll
  for (int i = 0; i < 4; ++i)
    Wt[(size_t)(bx + ty + i * 8) * N + by + tx] = f2bf(tile[tx][ty + i * 8]);
}

// ---------------------------------------------------------------------------
// Per-head V transpose: Vp [B,S,D] bf16 -> Vt [B*H][DEPTH][S] bf16
// One block per (s-tile of 64, bh).
// ---------------------------------------------------------------------------
__global__ __launch_bounds__(256) void transpose_v(const unsigned short* __restrict__ Vp,
                                                   unsigned short* __restrict__ Vt) {
  __shared__ unsigned short tile[64][72];  // tile[d][s_local]
  int tid = threadIdx.x;
  int sb = blockIdx.x;   // 0..31
  int bh = blockIdx.y;   // 0..63
  int b = bh >> 4, h = bh & 15;
  int s0 = sb * 64;
  // load 64 rows (s) x 64 cols (d), scatter-transpose into LDS
#pragma unroll
  for (int rep = 0; rep < 2; ++rep) {
    int idx = rep * 256 + tid;
    int r = idx >> 3, c8 = idx & 7;
    us8 v = *(const us8*)(Vp + (size_t)(b * S_LEN + s0 + r) * D_MODEL + h * DEPTH + c8 * 8);
#pragma unroll
    for (int e = 0; e < 8; ++e) tile[c8 * 8 + e][r] = v[e];
  }
  __syncthreads();
  // write out rows of V^T coalesced
#pragma unroll
  for (int rep = 0; rep < 2; ++rep) {
    int idx = rep * 256 + tid;
    int d = idx >> 3, c8 = idx & 7;
    us8 v = *(const us8*)&tile[d][c8 * 8];
    *(us8*)(Vt + ((size_t)(bh * DEPTH + d)) * S_LEN + s0 + c8 * 8) = v;
  }
}

// ---------------------------------------------------------------------------
// GEMM:  C[M][N] = A[M][K] @ Bt[N][K]^T + bias
// ---------------------------------------------------------------------------
template <bool A_IS_F32, bool OUT_F32>
__global__ __launch_bounds__(256) void gemm_bt(const void* __restrict__ Aptr,
                                               const unsigned short* __restrict__ Bt,
                                               const float* __restrict__ bias,
                                               void* __restrict__ Cptr,
                                               int M, int N, int K) {
  __shared__ unsigned short a_lds[128][72];
  __shared__ unsigned short b_lds[128][72];

  int tid = threadIdx.x;
  int wave = tid >> 6, lane = tid & 63;
  int l15 = lane & 15, lg = lane >> 4;
  int row0 = blockIdx.x * 128;
  int col0 = blockIdx.y * 128;
  int wm = wave >> 1, wn = wave & 1;

  const float* Af = (const float*)Aptr;
  const unsigned short* Ah = (const unsigned short*)Aptr;

  f32x4 acc[4][4] = {};

  for (int k0 = 0; k0 < K; k0 += 64) {
    __syncthreads();
    if constexpr (A_IS_F32) {
      int r = tid >> 4, c4 = tid & 15;
#pragma unroll
      for (int rep = 0; rep < 8; ++rep) {
        f32x4 v = *(const f32x4*)(Af + (size_t)(row0 + rep * 16 + r) * K + k0 + c4 * 4);
        us4 h = {f2bf(v[0]), f2bf(v[1]), f2bf(v[2]), f2bf(v[3])};
        *(us4*)&a_lds[rep * 16 + r][c4 * 4] = h;
      }
    } else {
      int r = tid >> 3, c8 = tid & 7;
#pragma unroll
      for (int rep = 0; rep < 4; ++rep) {
        us8 v = *(const us8*)(Ah + (size_t)(row0 + rep * 32 + r) * K + k0 + c8 * 8);
        *(us8*)&a_lds[rep * 32 + r][c8 * 8] = v;
      }
    }
    {
      int r = tid >> 3, c8 = tid & 7;
#pragma unroll
      for (int rep = 0; rep < 4; ++rep) {
        us8 v = *(const us8*)(Bt + (size_t)(col0 + rep * 32 + r) * K + k0 + c8 * 8);
        *(us8*)&b_lds[rep * 32 + r][c8 * 8] = v;
      }
    }
    __syncthreads();
#pragma unroll
    for (int kk = 0; kk < 2; ++kk) {
      bf16x8 af[4], bfr[4];
#pragma unroll
      for (int i = 0; i < 4; ++i)
        af[i] = *(const bf16x8*)&a_lds[wm * 64 + i * 16 + l15][kk * 32 + lg * 8];
#pragma unroll
      for (int j = 0; j < 4; ++j)
        bfr[j] = *(const bf16x8*)&b_lds[wn * 64 + j * 16 + l15][kk * 32 + lg * 8];
#pragma unroll
      for (int i = 0; i < 4; ++i)
#pragma unroll
        for (int j = 0; j < 4; ++j)
          acc[i][j] = __builtin_amdgcn_mfma_f32_16x16x32_bf16(af[i], bfr[j], acc[i][j], 0, 0, 0);
    }
  }

#pragma unroll
  for (int i = 0; i < 4; ++i) {
#pragma unroll
    for (int j = 0; j < 4; ++j) {
      int col = col0 + wn * 64 + j * 16 + l15;
      float bv = bias[col];
#pragma unroll
      for (int r = 0; r < 4; ++r) {
        int row = row0 + wm * 64 + i * 16 + lg * 4 + r;
        float v = acc[i][j][r] + bv;
        if constexpr (OUT_F32)
          ((float*)Cptr)[(size_t)row * N + col] = v;
        else
          ((unsigned short*)Cptr)[(size_t)row * N + col] = f2bf(v);
      }
    }
  }
}

// ---------------------------------------------------------------------------
// Causal flash attention. Q/K bf16 [B,S,D]; V^T bf16 [B*H][DEPTH][S].
// Block = 256 thr (4 waves x 16 q-rows), QBLK=64, KVBLK=64.
// Pairing: block handles q-tiles (p, 31-p) -> uniform 33 kv-steps/block.
// Double-buffered K/V^T staging, one barrier per kv-tile, reg-staged
// issue-early/write-late (T14). XCD-bijective swizzle clusters bh per XCD.
// ---------------------------------------------------------------------------
__global__ __launch_bounds__(256) void attn_kernel(const unsigned short* __restrict__ Qp,
                                                   const unsigned short* __restrict__ Kp,
                                                   const unsigned short* __restrict__ Vt,
                                                   unsigned short* __restrict__ Op) {
  __shared__ unsigned short k_lds[2][64][72];
  __shared__ unsigned short vt_lds[2][64][72];   // [d][k]
  __shared__ unsigned short p_lds[4][16][72];

  int tid = threadIdx.x;
  int w = tid >> 6, lane = tid & 63;
  int l15 = lane & 15, lg = lane >> 4;

  int bid = blockIdx.x + (blockIdx.y << 4);      // 0..1023
  int swz = (bid & 7) * 128 + (bid >> 3);        // bijective (1024 % 8 == 0)
  int pairIdx = swz & 15;                        // 0..15
  int bh = swz >> 4;                             // 0..63
  int b = bh >> 4, h = bh & 15;

  const unsigned short* Kbase = Kp + (size_t)b * S_LEN * D_MODEL + h * DEPTH;
  const unsigned short* Vbase = Vt + (size_t)bh * DEPTH * S_LEN;

  int r = tid >> 2, cb = (tid & 3) * 16;         // staging coords
  const unsigned short* krow = Kbase + (size_t)r * D_MODEL + cb;
  const unsigned short* vrow = Vbase + (size_t)r * S_LEN + cb;

  const float scale = 0.125f;  // 1/sqrt(64)

  for (int half = 0; half < 2; ++half) {
    int qb = (half == 0) ? pairIdx : (31 - pairIdx);
    int q0 = qb * 64;

    // Q fragments (A-frag: row = lane&15, k = lg*8..)
    bf16x8 qf0, qf1;
    {
      const unsigned short* qp =
          Qp + ((size_t)(b * S_LEN + q0 + w * 16 + l15)) * D_MODEL + h * DEPTH;
      qf0 = *(const bf16x8*)(qp + lg * 8);
      qf1 = *(const bf16x8*)(qp + 32 + lg * 8);
    }

    float m_run[4], l_run[4];
    f32x4 acc_o[4];
#pragma unroll
    for (int rr = 0; rr < 4; ++rr) { m_run[rr] = -1e30f; l_run[rr] = 0.f; }
#pragma unroll
    for (int d = 0; d < 4; ++d) acc_o[d] = (f32x4){0.f, 0.f, 0.f, 0.f};

    // ---- prologue: stage tile 0 into buf 0 ----
    us8 ka = *(const us8*)krow;
    us8 kb2 = *(const us8*)(krow + 8);
    us8 va = *(const us8*)vrow;
    us8 vb2 = *(const us8*)(vrow + 8);
    __syncthreads();  // prior half's readers done with LDS
    *(us8*)&k_lds[0][r][cb] = ka;
    *(us8*)&k_lds[0][r][cb + 8] = kb2;
    *(us8*)&vt_lds[0][r][cb] = va;
    *(us8*)&vt_lds[0][r][cb + 8] = vb2;

    for (int kb = 0; kb <= qb; ++kb) {
      int cur = kb & 1;
      __syncthreads();  // buf[cur] writes visible; buf[cur^1] readers done
      bool more = kb < qb;
      if (more) {
        // issue next tile's global loads early (latency hides under compute)
        size_t koff = (size_t)(kb + 1) * 64;
        ka = *(const us8*)(krow + koff * D_MODEL);
        kb2 = *(const us8*)(krow + koff * D_MODEL + 8);
        va = *(const us8*)(vrow + koff);
        vb2 = *(const us8*)(vrow + koff + 8);
      }

      // ---- S = Q @ K^T ----
      f32x4 s[4];
#pragma unroll
      for (int nf = 0; nf < 4; ++nf) s[nf] = (f32x4){0.f, 0.f, 0.f, 0.f};
#pragma unroll
      for (int nf = 0; nf < 4; ++nf) {
        bf16x8 kf0 = *(const bf16x8*)&k_lds[cur][nf * 16 + l15][lg * 8];
        bf16x8 kf1 = *(const bf16x8*)&k_lds[cur][nf * 16 + l15][32 + lg * 8];
        s[nf] = __builtin_amdgcn_mfma_f32_16x16x32_bf16(qf0, kf0, s[nf], 0, 0, 0);
        s[nf] = __builtin_amdgcn_mfma_f32_16x16x32_bf16(qf1, kf1, s[nf], 0, 0, 0);
      }

      // ---- scale + causal mask ----
      bool diag = (kb == qb);
      float sv[4][4];
#pragma unroll
      for (int nf = 0; nf < 4; ++nf)
#pragma unroll
        for (int rr = 0; rr < 4; ++rr) {
          float x = s[nf][rr] * scale;
          if (diag) {
            int qrow = w * 16 + lg * 4 + rr;
            int krow2 = nf * 16 + l15;
            if (krow2 > qrow) x = -1e10f;
          }
          sv[nf][rr] = x;
        }

      // ---- online softmax ----
      float mnew[4], corr[4], psum[4];
#pragma unroll
      for (int rr = 0; rr < 4; ++rr) {
        float mx = fmaxf(fmaxf(sv[0][rr], sv[1][rr]), fmaxf(sv[2][rr], sv[3][rr]));
#pragma unroll
        for (int off = 1; off < 16; off <<= 1)
          mx = fmaxf(mx, __shfl_xor(mx, off, 16));
        mnew[rr] = fmaxf(m_run[rr], mx);
        corr[rr] = __expf(m_run[rr] - mnew[rr]);
        m_run[rr] = mnew[rr];
      }
#pragma unroll
      for (int rr = 0; rr < 4; ++rr) psum[rr] = 0.f;
#pragma unroll
      for (int nf = 0; nf < 4; ++nf)
#pragma unroll
        for (int rr = 0; rr < 4; ++rr) {
          float p = __expf(sv[nf][rr] - mnew[rr]);
          psum[rr] += p;
          p_lds[w][lg * 4 + rr][nf * 16 + l15] = f2bf(p);
        }
#pragma unroll
      for (int rr = 0; rr < 4; ++rr) {
        float ps = psum[rr];
#pragma unroll
        for (int off = 1; off < 16; off <<= 1)
          ps += __shfl_xor(ps, off, 16);
        l_run[rr] = l_run[rr] * corr[rr] + ps;
      }
#pragma unroll
      for (int d = 0; d < 4; ++d)
#pragma unroll
        for (int rr = 0; rr < 4; ++rr) acc_o[d][rr] *= corr[rr];

      // ---- O += P @ V ----
#pragma unroll
      for (int kk = 0; kk < 2; ++kk) {
        bf16x8 pf = *(const bf16x8*)&p_lds[w][l15][kk * 32 + lg * 8];
#pragma unroll
        for (int d = 0; d < 4; ++d) {
          bf16x8 vf = *(const bf16x8*)&vt_lds[cur][d * 16 + l15][kk * 32 + lg * 8];
          acc_o[d] = __builtin_amdgcn_mfma_f32_16x16x32_bf16(pf, vf, acc_o[d], 0, 0, 0);
        }
      }

      // ---- write next tile into the other buffer (late write) ----
      if (more) {
        int nb = cur ^ 1;
        *(us8*)&k_lds[nb][r][cb] = ka;
        *(us8*)&k_lds[nb][r][cb + 8] = kb2;
        *(us8*)&vt_lds[nb][r][cb] = va;
        *(us8*)&vt_lds[nb][r][cb + 8] = vb2;
      }
    }

    // ---- finalize ----
#pragma unroll
    for (int rr = 0; rr < 4; ++rr) {
      float inv = 1.0f / l_run[rr];
      int qrow = q0 + w * 16 + lg * 4 + rr;
      unsigned short* op = Op + ((size_t)(b * S_LEN + qrow)) * D_MODEL + h * DEPTH;
#pragma unroll
      for (int d = 0; d < 4; ++d)
        op[d * 16 + l15] = f2bf(acc_o[d][rr] * inv);
    }
  }
}

// ---------------------------------------------------------------------------
extern "C" void kernel_launch(void* const* d_in, const int* in_sizes, int n_in,
                              void* d_out, int out_size, void* d_ws, size_t ws_size,
                              hipStream_t stream) {
  const float* q  = (const float*)d_in[0];
  const float* v  = (const float*)d_in[1];
  const float* k  = (const float*)d_in[2];
  const float* Wq = (const float*)d_in[3];
  const float* bq = (const float*)d_in[4];
  const float* Wk = (const float*)d_in[5];
  const float* bk = (const float*)d_in[6];
  const float* Wv = (const float*)d_in[7];
  const float* bv = (const float*)d_in[8];
  const float* Wo = (const float*)d_in[9];
  const float* bo = (const float*)d_in[10];

  char* ws = (char*)d_ws;
  const size_t WSZ = (size_t)D_MODEL * D_MODEL * 2;        // 2 MB per weight
  const size_t XSZ = (size_t)BATCH * S_LEN * D_MODEL * 2;  // 16 MB per activation
  unsigned short* Wqt = (unsigned short*)(ws);
  unsigned short* Wkt = (unsigned short*)(ws + WSZ);
  unsigned short* Wvt = (unsigned short*)(ws + 2 * WSZ);
  unsigned short* Wot = (unsigned short*)(ws + 3 * WSZ);
  unsigned short* Qp  = (unsigned short*)(ws + 4 * WSZ);
  unsigned short* Kp  = (unsigned short*)(ws + 4 * WSZ + XSZ);
  unsigned short* Vp  = (unsigned short*)(ws + 4 * WSZ + 2 * XSZ);
  unsigned short* Vtp = (unsigned short*)(ws + 4 * WSZ + 3 * XSZ);
  unsigned short* AO  = Vp;  // alias: Vp fully consumed by transpose_v before attn writes AO

  dim3 tb(32, 8);
  dim3 tg(D_MODEL / 32, D_MODEL / 32);
  hipLaunchKernelGGL(transpose_cast, tg, tb, 0, stream, Wq, Wqt, D_MODEL);
  hipLaunchKernelGGL(transpose_cast, tg, tb, 0, stream, Wk, Wkt, D_MODEL);
  hipLaunchKernelGGL(transpose_cast, tg, tb, 0, stream, Wv, Wvt, D_MODEL);
  hipLaunchKernelGGL(transpose_cast, tg, tb, 0, stream, Wo, Wot, D_MODEL);

  const int M = BATCH * S_LEN;
  dim3 gg(M / 128, D_MODEL / 128);
  hipLaunchKernelGGL((gemm_bt<true, false>), gg, dim3(256), 0, stream,
                     (const void*)q, Wqt, bq, (void*)Qp, M, D_MODEL, D_MODEL);
  hipLaunchKernelGGL((gemm_bt<true, false>), gg, dim3(256), 0, stream,
                     (const void*)k, Wkt, bk, (void*)Kp, M, D_MODEL, D_MODEL);
  hipLaunchKernelGGL((gemm_bt<true, false>), gg, dim3(256), 0, stream,
                     (const void*)v, Wvt, bv, (void*)Vp, M, D_MODEL, D_MODEL);

  hipLaunchKernelGGL(transpose_v, dim3(S_LEN / 64, BATCH * N_HEADS), dim3(256), 0, stream,
                     Vp, Vtp);

  hipLaunchKernelGGL(attn_kernel, dim3(16, BATCH * N_HEADS), dim3(256), 0, stream,
                     Qp, Kp, Vtp, AO);

  hipLaunchKernelGGL((gemm_bt<false, true>), gg, dim3(256), 0, stream,
                     (const void*)AO, Wot, bo, d_out, M, D_MODEL, D_MODEL);
}